// Round 6
// baseline (1005.439 us; speedup 1.0000x reference)
//
#include <hip/hip_runtime.h>
#include <hip/hip_bf16.h>
#include <stdint.h>

typedef __bf16 bf16x8 __attribute__((ext_vector_type(8)));
typedef float  f32x4  __attribute__((ext_vector_type(4)));
typedef unsigned short u16;

__device__ __forceinline__ u16 f2bf(float f) {
    return __builtin_bit_cast(u16, __float2bfloat16(f));
}

__device__ __forceinline__ void gload16(const void* g, void* l) {
    __builtin_amdgcn_global_load_lds(
        (const __attribute__((address_space(1))) void*)g,
        (__attribute__((address_space(3))) void*)l,
        16, 0, 0);
}

// ---------------- quantization pipeline ----------------

__global__ void zero3_k(unsigned int* p) {
    if (threadIdx.x < 3) p[threadIdx.x] = 0u;
}

__global__ void maxabs_k(const float* __restrict__ w, int n, unsigned int* __restrict__ out) {
    const int tid = threadIdx.x;
    float m = 0.f;
    for (int i = blockIdx.x * blockDim.x + tid; i < n; i += gridDim.x * blockDim.x)
        m = fmaxf(m, fabsf(w[i]));
    #pragma unroll
    for (int off = 32; off > 0; off >>= 1)
        m = fmaxf(m, __shfl_down(m, off));
    __shared__ float red[4];
    if ((tid & 63) == 0) red[tid >> 6] = m;
    __syncthreads();
    if (tid == 0) {
        m = fmaxf(fmaxf(red[0], red[1]), fmaxf(red[2], red[3]));
        atomicMax(out, __float_as_uint(m));  // all values >=0: uint order == float order
    }
}

// w_q = clip(rint(w/scale), -n, n)*scale (fp32, matches jnp), emitted in
// MFMA-frag-PACKED layout: chunk[(k/32)*(rows/16) + r/16][lane][8] where
// lane = (r&15) + ((k>>3)&3)*16, elem = k&7. A wave's B-frag load is then
// 64 lanes x consecutive 16B = one coalesced 1KB block.
__global__ void quant_pack_k(const float* __restrict__ w, int rows, int K, int l2k8,
                             const unsigned int* __restrict__ maxbits, float qn,
                             u16* __restrict__ out) {
    const float scale = __uint_as_float(*maxbits) / qn;
    const int nchunk = rows * (K >> 3);
    const int NB16 = rows >> 4;
    for (int i = blockIdx.x * blockDim.x + threadIdx.x; i < nchunk;
         i += gridDim.x * blockDim.x) {
        const int r  = i >> l2k8;
        const int k8 = i & ((1 << l2k8) - 1);
        const float* src = w + (size_t)r * K + (k8 << 3);
        u16 tmp[8];
        #pragma unroll
        for (int j = 0; j < 8; ++j) {
            float q = rintf(src[j] / scale);     // RNE == jnp.round
            q = fminf(qn, fmaxf(-qn, q));
            tmp[j] = f2bf(q * scale);
        }
        const size_t chunk = ((size_t)(k8 >> 2) * NB16 + (r >> 4)) * 64
                             + (r & 15) + ((k8 & 3) << 4);
        *(uint4*)(out + chunk * 8) = *(const uint4*)tmp;
    }
}

__global__ void cvt_k(const float* __restrict__ x, u16* __restrict__ o, long n) {
    const long stride = (long)gridDim.x * blockDim.x * 4;
    for (long i = ((long)blockIdx.x * blockDim.x + threadIdx.x) * 4; i < n; i += stride) {
        float4 v = *(const float4*)(x + i);
        unsigned int lo = (unsigned int)f2bf(v.x) | ((unsigned int)f2bf(v.y) << 16);
        unsigned int hi = (unsigned int)f2bf(v.z) | ((unsigned int)f2bf(v.w) << 16);
        *(uint2*)(o + i) = make_uint2(lo, hi);
    }
}

// ---------------- GEMM: C = A(MxK) * B(NxK)^T + bias, LeakyReLU ----------------
// 256x256 tile, BK=32, 8 waves (2M x 4N), per-wave 128x64 = 8x4 16x16x32 frags.
// B is NOT staged in LDS: packed-frag B loads go global->reg (4 coalesced 1KB
// b128 per wave per tile, L2-resident 1MB panel per XCD), prefetched 1 tile
// ahead. LDS holds only A (4-slot ring of 16KB => 64KB): traffic 64KB read +
// 16KB write per K-32 < 1082cy MFMA => MFMA-bound reachable. ONE raw barrier +
// one counted vmcnt(6) per tile (queue at tile-k head = [A(k+1),B(k),A(k+2)]
// = 8 ops; vmcnt(6) certifies A(k); compiler's own waits cover B). Frag reads
// are plain loads (compiler emits counted lgkmcnt + interleaves with MFMA).
// Per-XCD block map: bn = bid&7 (fixed B panel per XCD), bm = bid>>3.

#define STAGE_A(kt)                                                            \
  do {                                                                         \
    const size_t _gk = (size_t)(kt) * 32;                                      \
    gload16(gA + _gk,              &ring[(kt) & 3][wave * 512]);               \
    gload16(gA + rowHalf + _gk,    &ring[(kt) & 3][4096 + wave * 512]);        \
  } while (0)

#define LOAD_B(kt, DST)                                                        \
  do {                                                                         \
    const u16* _p = pBw + (size_t)(kt) * kStrideB + (lane << 3);               \
    DST[0] = *(const bf16x8*)(_p);                                             \
    DST[1] = *(const bf16x8*)(_p + 512);                                       \
    DST[2] = *(const bf16x8*)(_p + 1024);                                      \
    DST[3] = *(const bf16x8*)(_p + 1536);                                      \
  } while (0)

#define TILE(kt, CUR, NXT)                                                     \
  do {                                                                         \
    asm volatile("s_waitcnt vmcnt(6)" ::: "memory");                           \
    __builtin_amdgcn_s_barrier();                                              \
    asm volatile("" ::: "memory");                                             \
    if ((kt) + 1 < NT) LOAD_B((kt) + 1, NXT);                                  \
    if ((kt) + 3 < NT) STAGE_A((kt) + 3);                                      \
    const u16* sA = &ring[(kt) & 3][0];                                        \
    bf16x8 afr[8];                                                             \
    _Pragma("unroll") for (int m = 0; m < 8; ++m)                              \
        afr[m] = *(const bf16x8*)(sA + aoff + m * 512);                        \
    __builtin_amdgcn_s_setprio(1);                                             \
    _Pragma("unroll") for (int m = 0; m < 8; ++m)                              \
      _Pragma("unroll") for (int n = 0; n < 4; ++n)                            \
        acc[m][n] = __builtin_amdgcn_mfma_f32_16x16x32_bf16(afr[m], CUR[n],    \
                                                            acc[m][n], 0,0,0); \
    __builtin_amdgcn_s_setprio(0);                                             \
  } while (0)

template<int BF16OUT>
__global__ __launch_bounds__(512, 2)
void gemm_bg(const u16* __restrict__ A, const u16* __restrict__ pB,
             const float* __restrict__ bias, void* __restrict__ Cv,
             int M, int Nn, int K)
{
    __shared__ __align__(128) u16 ring[4][8192];   // A only: [slot][256 rows x 32 cols]
    __shared__ __align__(128) float epi[8][1088];  // epilogue transpose, per wave 68x16

    const int tid  = threadIdx.x;
    const int lane = tid & 63;
    const int wave = tid >> 6;
    const int wm = wave >> 2;   // 0..1 -> row offset wm*128
    const int wn = wave & 3;    // 0..3 -> col offset wn*64

    // per-XCD map: each XCD owns one 256-col B panel (L2-resident, packed 1MB)
    const int bn = (blockIdx.x & 7) << 8;
    const int bm = (blockIdx.x >> 3) << 8;

    // A staging: thread t -> row t>>2 (of a 128-row half), 16B slot t%4;
    // source col pre-swizzled slot^(row&3) (rule 21; matches frag-read swizzle)
    const int srow = tid >> 2;
    const int scol = (((tid & 3) ^ (srow & 3)) << 3);
    const u16* gA = A + (size_t)(bm + srow) * K + scol;
    const size_t rowHalf = (size_t)128 * K;

    // packed-B base for this wave: chunks [(kt)*(Nn/16) + wn*4 + n][lane][8]
    const int NB16 = Nn >> 4;
    const size_t kStrideB = (size_t)NB16 * 512;
    const u16* pBw = pB + (size_t)(wn * 4) * 512;
    const u16* pBw2 = pB + ((size_t)(bn >> 4) + wn * 4) * 512;  // bn offset in chunks
    pBw = pBw2;

    // A frag read offsets (u16 elems): row*32 + ((lane>>4) ^ (row&3))*8
    const int fr = lane & 15;
    const int slotp = (((lane >> 4) ^ (lane & 3)) << 3);
    const int aoff = (wm * 128 + fr) * 32 + slotp;   // + m*512 per m-frag

    f32x4 acc[8][4] = {};
    bf16x8 bA[4], bB[4];
    const int NT = K >> 5;   // 32 or 64, even

    // prologue: A tiles 0..2 staged, B tile 0 loaded (issue order safe for ledger)
    STAGE_A(0);
    STAGE_A(1);
    LOAD_B(0, bA);
    STAGE_A(2);

    for (int k = 0; k < NT; k += 2) {
        TILE(k,     bA, bB);
        TILE(k + 1, bB, bA);
    }

    // ---- coalesced epilogue through dedicated LDS (per-wave slice) ----
    // C/D frag layout (m89): col = lane&15, row = (lane>>4)*4 + j
    const int crow = (lane >> 4) << 2;
    const int ccol = lane & 15;
    float* lsw = &epi[wave][0];
    float bv[4];
    #pragma unroll
    for (int n = 0; n < 4; ++n) bv[n] = bias[bn + wn * 64 + n * 16 + ccol];

    const int erow = lane & 15;        // gather: lane -> row, col-group
    const int ecg  = lane >> 4;
    #pragma unroll
    for (int m = 0; m < 8; ++m) {
        #pragma unroll
        for (int n = 0; n < 4; ++n)
            #pragma unroll
            for (int j = 0; j < 4; ++j) {
                float v = acc[m][n][j] + bv[n];
                v = (v >= 0.f) ? v : 0.01f * v;
                lsw[(crow + j) * 68 + n * 16 + ccol] = v;
            }
        asm volatile("s_waitcnt lgkmcnt(0)" ::: "memory");
        const float* src = lsw + erow * 68 + ecg * 16;
        const size_t grow = (size_t)(bm + wm * 128 + m * 16 + erow);
        const int    gcol = bn + wn * 64 + ecg * 16;
        if (BF16OUT) {
            u16 tmp[16];
            #pragma unroll
            for (int e = 0; e < 16; ++e) tmp[e] = f2bf(src[e]);
            u16* dst = (u16*)Cv + grow * Nn + gcol;
            *(uint4*)dst       = ((const uint4*)tmp)[0];
            *(uint4*)(dst + 8) = ((const uint4*)tmp)[1];
        } else {
            float* dst = (float*)Cv + grow * Nn + gcol;
            #pragma unroll
            for (int e = 0; e < 4; ++e)
                ((float4*)dst)[e] = ((const float4*)src)[e];
        }
        asm volatile("" ::: "memory");   // keep m-chunks ordered (WAR on lsw)
    }
}

// ---------------- launch ----------------

extern "C" void kernel_launch(void* const* d_in, const int* in_sizes, int n_in,
                              void* d_out, int out_size, void* d_ws, size_t ws_size,
                              hipStream_t stream) {
    const float* x  = (const float*)d_in[0];
    const float* W0 = (const float*)d_in[1];
    const float* b0 = (const float*)d_in[2];
    const float* W1 = (const float*)d_in[3];
    const float* b1 = (const float*)d_in[4];
    const float* W2 = (const float*)d_in[5];
    const float* b2 = (const float*)d_in[6];

    const int N = 32768, D0 = 1024, D1 = 2048;

    char* ws = (char*)d_ws;
    u16* xbf = (u16*)ws;  ws += (size_t)N * D0 * 2;
    u16* h0  = (u16*)ws;  ws += (size_t)N * D1 * 2;
    u16* h1  = (u16*)ws;  ws += (size_t)N * D1 * 2;
    u16* w0q = (u16*)ws;  ws += (size_t)D1 * D0 * 2;
    u16* w1q = (u16*)ws;  ws += (size_t)D1 * D1 * 2;
    u16* w2q = (u16*)ws;  ws += (size_t)D1 * D1 * 2;
    unsigned int* scales = (unsigned int*)ws;

    zero3_k<<<1, 64, 0, stream>>>(scales);
    maxabs_k<<<256, 256, 0, stream>>>(W0, D1 * D0, scales + 0);
    maxabs_k<<<256, 256, 0, stream>>>(W1, D1 * D1, scales + 1);
    maxabs_k<<<256, 256, 0, stream>>>(W2, D1 * D1, scales + 2);
    // packed-frag quantized weights (l2k8 = log2(K/8))
    quant_pack_k<<<2048, 256, 0, stream>>>(W0, D1, D0, 7, scales + 0, 127.f, w0q);
    quant_pack_k<<<2048, 256, 0, stream>>>(W1, D1, D1, 8, scales + 1, 7.f, w1q);
    quant_pack_k<<<2048, 256, 0, stream>>>(W2, D1, D1, 8, scales + 2, 7.f, w2q);
    cvt_k<<<4096, 256, 0, stream>>>(x, xbf, (long)N * D0);

    const int blocks = (D1 / 256) * (N / 256);   // 8 bn * 128 bm = 1024
    gemm_bg<1><<<blocks, 512, 0, stream>>>(xbf, w0q, b0, h0, N, D1, D0);
    gemm_bg<1><<<blocks, 512, 0, stream>>>(h0, w1q, b1, h1, N, D1, D1);
    gemm_bg<0><<<blocks, 512, 0, stream>>>(h1, w2q, b2, d_out, N, D1, D1);
}